// Round 3
// baseline (652.276 us; speedup 1.0000x reference)
//
#include <hip/hip_runtime.h>

// LQR2: NS=32, NC=16, T=64, NB=512, NSC=48
// out: x[512][64][32] | u[512][64][16] | cost[512]
// ws:  K^T fp32 [512][64][32][16]  then k fp32 [512][64][16]
//
// R7: 2 problems per 512-thread block (grid 256, 1 block/CU, ~106 KB LDS).
//  Wave->role map permuted so the two issue-bound solver waves land on
//  DIFFERENT SIMDs (w3->SIMD3, w6->SIMD2) and each pairs with a wave that
//  is barrier-idle during the solve phase; phase-A tile load balanced
//  (5+3 / 4+4 / 3+qt / qt+5 per SIMD). Per-problem algorithm identical to R6.
// R6: 2 barriers/step; P0+P1 fused wave-local; solver does P4+vn.
// R5: lgkm-only in-loop barriers; LDS padding TP=40 bf16 / SQS=52 f32.
// R4: analytic cost during backward; wave-synchronous forward.

#define NSd 32
#define NCd 16
#define Td 64
#define NBd 512
#define NSCd 48
#define SQS 52  // padded row stride (floats) for sQ / sFf
#define TP 40   // padded row stride (bf16) for MFMA tiles

typedef __bf16 bf16x8 __attribute__((ext_vector_type(8)));
typedef __bf16 bf16x4 __attribute__((ext_vector_type(4)));
typedef float f32x4 __attribute__((ext_vector_type(4)));

#define MFMA16(a, b, c) __builtin_amdgcn_mfma_f32_16x16x32_bf16(a, b, c, 0, 0, 0)

#define XOFF ((size_t)0)
#define UOFF ((size_t)NBd * Td * NSd)
#define COFF (UOFF + (size_t)NBd * Td * NCd)

__device__ __forceinline__ float rdl(float v, int l) {
  return __uint_as_float(__builtin_amdgcn_readlane(__float_as_uint(v), l));
}

// LDS-only barrier: does NOT drain vmcnt; all in-loop cross-wave deps are LDS.
__device__ __forceinline__ void bar_lgkm() {
  asm volatile("s_waitcnt lgkmcnt(0)\n\ts_barrier" ::: "memory");
}

struct ProbBW {
  __bf16 Vh[32][TP], Vl[32][TP];
  __bf16 WTh[48][TP], WTl[48][TP];
  __bf16 Xh[32][TP], Xl[32][TP];
  __bf16 KTh[32][TP], KTl[32][TP];
  float Quu[16][17];
  float Qd[3][16][17];  // f32 handoff: (0,0)->0, (0,1)->1, (1,1)->2
  float qt[48];
  float vv[32];
};
struct ProbFW {  // overlays dead backward fragments
  float K2T[2][16 * 36];  // row stride 36 (bank-conflict pad, 16B aligned)
  float kv2[2][16];
  float d[32];
  float xs[32];
  float uu[16];
};
union ProbU {
  ProbBW bw;
  ProbFW fw;
};

// padded sQ store: linear float4 index i (of 576) -> row i/12, col (i%12)*4
#define SQSTORE(base, i, v)                      \
  do {                                           \
    int _r = (i) / 12, _c = (i) - _r * 12;       \
    *(float4*)&(base)[_r * SQS + _c * 4] = (v);  \
  } while (0)

__global__ __launch_bounds__(512, 2) void lqr_kernel(
    const float* __restrict__ x_init, const float* __restrict__ Qg,
    const float* __restrict__ pg, const float* __restrict__ Ag,
    const float* __restrict__ Bg, float* __restrict__ out,
    float* __restrict__ wsK, float* __restrict__ wskv) {
  const int tid = threadIdx.x;
  const int w = tid >> 6;
  const int lane = tid & 63;
  const int p = w >> 2;  // problem index within block
  // role map: w0..w7 -> 0,1,2,S | 2,1,S,0  (solvers on SIMD3 & SIMD2;
  // heavy I0 waves on SIMD0 & SIMD3; balanced per-SIMD tile load)
  const int role = (0x03123210u >> (w * 4)) & 0xF;
  const int b = blockIdx.x * 2 + p;
  const int gtid = (w & 3) * 64 + lane;  // [0,256) within problem group
  const int fn = lane & 15;
  const int quad = lane >> 4;
  const int k0 = quad * 8;

  __shared__ __attribute__((aligned(16))) float sQ[2][48 * SQS];
  __shared__ __attribute__((aligned(16))) float scx[2][Td][NSd];
  __shared__ __attribute__((aligned(16))) float sFf[NSd][SQS];  // shared A|B
  __shared__ __attribute__((aligned(16))) __bf16 FTh[48][TP];   // shared F^T
  __shared__ __attribute__((aligned(16))) __bf16 FTl[48][TP];
  __shared__ __attribute__((aligned(16))) ProbU U[2];
  __shared__ float scostp[2];

  // ---------------- setup ----------------
  for (int idx = tid; idx < 1536; idx += 512) {
    int i = idx / 48, j = idx - i * 48;
    sFf[i][j] = (j < 32) ? Ag[i * 32 + j] : Bg[i * 16 + (j - 32)];
  }
  for (int idx = tid; idx < 1536; idx += 512) {
    int a = idx >> 5, k = idx & 31;
    float f = (a < 32) ? Ag[k * 32 + a] : Bg[k * 16 + (a - 32)];
    __bf16 h = (__bf16)f;
    FTh[a][k] = h;
    FTl[a][k] = (__bf16)(f - (float)h);
  }
  for (int idx = gtid; idx < 1024; idx += 256) {
    int r = idx >> 5, c = idx & 31;
    __bf16 z = (__bf16)0.f;
    U[p].bw.Vh[r][c] = z; U[p].bw.Vl[r][c] = z;
    U[p].bw.Xh[r][c] = z; U[p].bw.Xl[r][c] = z;
    U[p].bw.KTh[r][c] = z; U[p].bw.KTl[r][c] = z;
  }
  if (gtid < 32) {
    scx[p][0][gtid] = x_init[b * 32 + gtid];
    U[p].bw.vv[gtid] = 0.f;
  }
  {  // stage Q[b,63]
    const float4* src = (const float4*)(Qg + ((size_t)b * Td + 63) * 2304);
    float4 v0 = src[gtid];
    float4 v1 = src[gtid + 256];
    SQSTORE(sQ[p], gtid, v0);
    SQSTORE(sQ[p], gtid + 256, v1);
    if (gtid < 64) {
      float4 v2 = src[gtid + 512];
      SQSTORE(sQ[p], gtid + 512, v2);
    }
  }
  float ppf = 0.f;
  if (role == 3 && lane < 48) ppf = pg[((size_t)b * Td + 63) * 48 + lane];
  __syncthreads();

  // cx rollout, wave-synchronous on role-0 wave of each problem
  if (role == 0) {
    for (int t2 = 0; t2 < Td - 1; ++t2) {
      if (lane < 32) {
        float acc = 0.f;
#pragma unroll
        for (int j = 0; j < 32; j += 4) {
          float4 a4 = *(const float4*)&sFf[lane][j];
          acc += a4.x * scx[p][t2][j] + a4.y * scx[p][t2][j + 1] +
                 a4.z * scx[p][t2][j + 2] + a4.w * scx[p][t2][j + 3];
        }
        scx[p][t2 + 1][lane] = acc;
      }
    }
  }
  __syncthreads();

  float cAcc = 0.f;  // solver lanes<32: sum_t 0.5*cx'(p + 0.5*Q*cx) terms
  float dAcc = 0.f;  // solver lane32: sum_t 0.5*qu.kt

  // ---------------- backward Riccati: 2 barriers/step ----------------
  for (int t = Td - 1; t >= 0; --t) {
    float4 pf0, pf1, pf2;
    float ppfn;
    if (t > 0) {
      if (role < 3) {  // 192 threads x 3 float4 = 576 = full Q tile
        const int ptid = role * 64 + lane;
        const float4* src = (const float4*)(Qg + ((size_t)b * Td + (t - 1)) * 2304);
        pf0 = src[ptid];
        pf1 = src[ptid + 192];
        pf2 = src[ptid + 384];
      } else if (lane < 48) {
        ppfn = pg[((size_t)b * Td + t - 1) * 48 + lane];
      }
    }

    // ---- Phase A: fused P0+P1 on tile waves (wave-local WT rows); qt on S ----
    if (role < 3) {
      const int I = role;
      // P0: WT row-block I = F_I^T · V (both col halves)
      bf16x8 aH = *(const bf16x8*)&FTh[16 * I + fn][k0];
      bf16x8 aL = *(const bf16x8*)&FTl[16 * I + fn][k0];
#pragma unroll
      for (int J = 0; J < 2; ++J) {
        bf16x8 bH = *(const bf16x8*)&U[p].bw.Vh[16 * J + fn][k0];
        bf16x8 bL = *(const bf16x8*)&U[p].bw.Vl[16 * J + fn][k0];
        f32x4 acc = {0.f, 0.f, 0.f, 0.f};
        acc = MFMA16(aL, bH, acc);
        acc = MFMA16(aH, bL, acc);
        acc = MFMA16(aH, bH, acc);
#pragma unroll
        for (int r = 0; r < 4; ++r) {
          float v = acc[r];
          __bf16 h = (__bf16)v;
          U[p].bw.WTh[16 * I + 4 * quad + r][16 * J + fn] = h;
          U[p].bw.WTl[16 * I + 4 * quad + r][16 * J + fn] = (__bf16)(v - (float)h);
        }
      }
      // P1 (same wave reads only its own WT rows; lgkm dep, no barrier)
      bf16x8 wH = *(const bf16x8*)&U[p].bw.WTh[16 * I + fn][k0];
      bf16x8 wL = *(const bf16x8*)&U[p].bw.WTl[16 * I + fn][k0];
      if (I == 2) {  // (2,2) -> Quu f32
        bf16x8 bH = *(const bf16x8*)&FTh[32 + fn][k0];
        bf16x8 bL = *(const bf16x8*)&FTl[32 + fn][k0];
        f32x4 acc;
#pragma unroll
        for (int r = 0; r < 4; ++r)
          acc[r] = sQ[p][(32 + 4 * quad + r) * SQS + 32 + fn];
        acc = MFMA16(wL, bH, acc);
        acc = MFMA16(wH, bL, acc);
        acc = MFMA16(wH, bH, acc);
#pragma unroll
        for (int r = 0; r < 4; ++r) U[p].bw.Quu[4 * quad + r][fn] = acc[r];
      } else {
        {  // diag tile (I,I) -> Qd[0] (I=0) / Qd[2] (I=1)
          bf16x8 bH = *(const bf16x8*)&FTh[16 * I + fn][k0];
          bf16x8 bL = *(const bf16x8*)&FTl[16 * I + fn][k0];
          f32x4 acc;
#pragma unroll
          for (int r = 0; r < 4; ++r)
            acc[r] = sQ[p][(16 * I + 4 * quad + r) * SQS + 16 * I + fn];
          acc = MFMA16(wL, bH, acc);
          acc = MFMA16(wH, bL, acc);
          acc = MFMA16(wH, bH, acc);
#pragma unroll
          for (int r = 0; r < 4; ++r) U[p].bw.Qd[I * 2][4 * quad + r][fn] = acc[r];
        }
        if (I == 0) {  // (0,1) -> Qd[1]
          bf16x8 bH = *(const bf16x8*)&FTh[16 + fn][k0];
          bf16x8 bL = *(const bf16x8*)&FTl[16 + fn][k0];
          f32x4 acc;
#pragma unroll
          for (int r = 0; r < 4; ++r)
            acc[r] = sQ[p][(4 * quad + r) * SQS + 16 + fn];
          acc = MFMA16(wL, bH, acc);
          acc = MFMA16(wH, bL, acc);
          acc = MFMA16(wH, bH, acc);
#pragma unroll
          for (int r = 0; r < 4; ++r) U[p].bw.Qd[1][4 * quad + r][fn] = acc[r];
        }
        {  // (I,2) -> X rows 16I..16I+15 (Qxu block, bf16 hi/lo)
          bf16x8 bH = *(const bf16x8*)&FTh[32 + fn][k0];
          bf16x8 bL = *(const bf16x8*)&FTl[32 + fn][k0];
          f32x4 acc;
#pragma unroll
          for (int r = 0; r < 4; ++r)
            acc[r] = sQ[p][(16 * I + 4 * quad + r) * SQS + 32 + fn];
          acc = MFMA16(wL, bH, acc);
          acc = MFMA16(wH, bL, acc);
          acc = MFMA16(wH, bH, acc);
#pragma unroll
          for (int r = 0; r < 4; ++r) {
            float v = acc[r];
            __bf16 h = (__bf16)v;
            U[p].bw.Xh[16 * I + 4 * quad + r][fn] = h;
            U[p].bw.Xl[16 * I + 4 * quad + r][fn] = (__bf16)(v - (float)h);
          }
        }
      }
    } else if (lane < 48) {  // solver wave: qt vector + cost const term
      float acc1 = ppf;  // p + Q*cxu
#pragma unroll
      for (int k = 0; k < 32; ++k) acc1 += sQ[p][k * SQS + lane] * scx[p][t][k];
      if (lane < 32) cAcc += 0.5f * scx[p][t][lane] * (acc1 + ppf);
      float acc = acc1;
#pragma unroll
      for (int k = 0; k < 32; ++k) acc += U[p].bw.vv[k] * sFf[k][lane];
      U[p].bw.qt[lane] = acc;
    }
    bar_lgkm();  // B2

    // ---- Phase B: tile waves commit sQ; solver solves + Vn + vn ----
    if (t > 0) {
      if (role < 3) {
        const int ptid = role * 64 + lane;
        SQSTORE(sQ[p], ptid, pf0);
        SQSTORE(sQ[p], ptid + 192, pf1);
        SQSTORE(sQ[p], ptid + 384, pf2);
      } else if (lane < 48) {
        ppf = ppfn;
      }
    }
    if (role == 3) {
      // solve Quu * X = [Qux | qu] via readlane-broadcast elimination
      float rhs[16];
      if (lane < 32) {
        bf16x8 xh0 = *(const bf16x8*)&U[p].bw.Xh[lane][0];
        bf16x8 xh1 = *(const bf16x8*)&U[p].bw.Xh[lane][8];
        bf16x8 xl0 = *(const bf16x8*)&U[p].bw.Xl[lane][0];
        bf16x8 xl1 = *(const bf16x8*)&U[p].bw.Xl[lane][8];
#pragma unroll
        for (int i = 0; i < 8; ++i) {
          rhs[i] = (float)xh0[i] + (float)xl0[i];
          rhs[8 + i] = (float)xh1[i] + (float)xl1[i];
        }
      } else {
#pragma unroll
        for (int i = 0; i < 16; ++i) rhs[i] = U[p].bw.qt[32 + i];
      }
      float quu[16];
#pragma unroll
      for (int i = 0; i < 16; ++i) quu[i] = U[p].bw.Quu[i][fn];
#pragma unroll
      for (int r = 0; r < 15; ++r) {
        float inv = __builtin_amdgcn_rcpf(rdl(quu[r], r));
#pragma unroll
        for (int i = r + 1; i < 16; ++i) {
          float m = rdl(quu[i], r) * inv;
          rhs[i] -= m * rhs[r];
          quu[i] -= m * quu[r];
        }
      }
      float xx[16];
#pragma unroll
      for (int r = 15; r >= 0; --r) {
        float s = rhs[r];
#pragma unroll
        for (int c = r + 1; c < 16; ++c) s -= rdl(quu[r], c) * xx[c];
        xx[r] = s * __builtin_amdgcn_rcpf(rdl(quu[r], r));
      }
      if (lane < 32) {  // Kt^T bf16 to LDS + fp32 K to ws
        bf16x8 h0, l0, h1, l1;
#pragma unroll
        for (int u = 0; u < 8; ++u) {
          float kv = -xx[u];
          __bf16 hh = (__bf16)kv;
          h0[u] = hh; l0[u] = (__bf16)(kv - (float)hh);
          float kv2 = -xx[8 + u];
          __bf16 hh2 = (__bf16)kv2;
          h1[u] = hh2; l1[u] = (__bf16)(kv2 - (float)hh2);
        }
        *(bf16x8*)&U[p].bw.KTh[lane][0] = h0;
        *(bf16x8*)&U[p].bw.KTh[lane][8] = h1;
        *(bf16x8*)&U[p].bw.KTl[lane][0] = l0;
        *(bf16x8*)&U[p].bw.KTl[lane][8] = l1;
        float4* dst = (float4*)(wsK + (((size_t)b * Td + t) * 32 + lane) * 16);
        float4 v0 = {-xx[0], -xx[1], -xx[2], -xx[3]};
        float4 v1 = {-xx[4], -xx[5], -xx[6], -xx[7]};
        float4 v2 = {-xx[8], -xx[9], -xx[10], -xx[11]};
        float4 v3 = {-xx[12], -xx[13], -xx[14], -xx[15]};
        dst[0] = v0; dst[1] = v1; dst[2] = v2; dst[3] = v3;
      } else if (lane == 32) {  // kt to ws; cost delta term
        float4* dst = (float4*)(wskv + ((size_t)b * Td + t) * 16);
        float4 v0 = {-xx[0], -xx[1], -xx[2], -xx[3]};
        float4 v1 = {-xx[4], -xx[5], -xx[6], -xx[7]};
        float4 v2 = {-xx[8], -xx[9], -xx[10], -xx[11]};
        float4 v3 = {-xx[12], -xx[13], -xx[14], -xx[15]};
        dst[0] = v0; dst[1] = v1; dst[2] = v2; dst[3] = v3;
        float s = 0.f;
#pragma unroll
        for (int i = 0; i < 16; ++i) s += U[p].bw.qt[32 + i] * xx[i];
        dAcc -= 0.5f * s;
      }
      {  // vn = qx + Qxu*kt using local xx (kt lives in lane 32's xx)
        float acc = 0.f;
        bf16x8 xh0, xh1, xl0, xl1;
        if (lane < 32) {
          xh0 = *(const bf16x8*)&U[p].bw.Xh[lane][0];
          xh1 = *(const bf16x8*)&U[p].bw.Xh[lane][8];
          xl0 = *(const bf16x8*)&U[p].bw.Xl[lane][0];
          xl1 = *(const bf16x8*)&U[p].bw.Xl[lane][8];
          acc = U[p].bw.qt[lane];
        }
#pragma unroll
        for (int u = 0; u < 8; ++u) {
          float kt0 = -rdl(xx[u], 32);
          float kt1 = -rdl(xx[8 + u], 32);
          if (lane < 32) {
            acc += ((float)xh0[u] + (float)xl0[u]) * kt0;
            acc += ((float)xh1[u] + (float)xl1[u]) * kt1;
          }
        }
        if (lane < 32) U[p].bw.vv[lane] = acc;
      }
      // P4 on the solver wave: KT just written by this wave (lgkm dep only)
      {  // V(0,0) = Qd[0] + Xrows0-15 · KTcols0-15
        bf16x8 aH = *(const bf16x8*)&U[p].bw.Xh[fn][k0];
        bf16x8 aL = *(const bf16x8*)&U[p].bw.Xl[fn][k0];
        bf16x8 bH = *(const bf16x8*)&U[p].bw.KTh[fn][k0];
        bf16x8 bL = *(const bf16x8*)&U[p].bw.KTl[fn][k0];
        f32x4 acc;
#pragma unroll
        for (int r = 0; r < 4; ++r) acc[r] = U[p].bw.Qd[0][4 * quad + r][fn];
        acc = MFMA16(aL, bH, acc);
        acc = MFMA16(aH, bL, acc);
        acc = MFMA16(aH, bH, acc);
#pragma unroll
        for (int r = 0; r < 4; ++r) {
          float v = acc[r];
          __bf16 h = (__bf16)v;
          U[p].bw.Vh[4 * quad + r][fn] = h;
          U[p].bw.Vl[4 * quad + r][fn] = (__bf16)(v - (float)h);
        }
      }
      {  // V(1,1) = Qd[2] + Xrows16-31 · KTcols16-31
        bf16x8 aH = *(const bf16x8*)&U[p].bw.Xh[16 + fn][k0];
        bf16x8 aL = *(const bf16x8*)&U[p].bw.Xl[16 + fn][k0];
        bf16x8 bH = *(const bf16x8*)&U[p].bw.KTh[16 + fn][k0];
        bf16x8 bL = *(const bf16x8*)&U[p].bw.KTl[16 + fn][k0];
        f32x4 acc;
#pragma unroll
        for (int r = 0; r < 4; ++r) acc[r] = U[p].bw.Qd[2][4 * quad + r][fn];
        acc = MFMA16(aL, bH, acc);
        acc = MFMA16(aH, bL, acc);
        acc = MFMA16(aH, bH, acc);
#pragma unroll
        for (int r = 0; r < 4; ++r) {
          float v = acc[r];
          __bf16 h = (__bf16)v;
          U[p].bw.Vh[16 + 4 * quad + r][16 + fn] = h;
          U[p].bw.Vl[16 + 4 * quad + r][16 + fn] = (__bf16)(v - (float)h);
        }
      }
      {  // V(0,1) = Qd[1] + Xrows0-15 · KTcols16-31, plus symmetric mirror
        bf16x8 aH = *(const bf16x8*)&U[p].bw.Xh[fn][k0];
        bf16x8 aL = *(const bf16x8*)&U[p].bw.Xl[fn][k0];
        bf16x8 bH = *(const bf16x8*)&U[p].bw.KTh[16 + fn][k0];
        bf16x8 bL = *(const bf16x8*)&U[p].bw.KTl[16 + fn][k0];
        f32x4 acc;
#pragma unroll
        for (int r = 0; r < 4; ++r) acc[r] = U[p].bw.Qd[1][4 * quad + r][fn];
        acc = MFMA16(aL, bH, acc);
        acc = MFMA16(aH, bL, acc);
        acc = MFMA16(aH, bH, acc);
        bf16x4 th, tl;
#pragma unroll
        for (int r = 0; r < 4; ++r) {
          float v = acc[r];
          __bf16 h = (__bf16)v;
          __bf16 l = (__bf16)(v - (float)h);
          U[p].bw.Vh[4 * quad + r][16 + fn] = h;
          U[p].bw.Vl[4 * quad + r][16 + fn] = l;
          th[r] = h; tl[r] = l;
        }
        *(bf16x4*)&U[p].bw.Vh[16 + fn][4 * quad] = th;  // mirror (V symmetric)
        *(bf16x4*)&U[p].bw.Vl[16 + fn][4 * quad] = tl;
      }
    }
    bar_lgkm();  // B3 (end of step)
  }

  // ---------------- cost partial, then union flips to forward ----------------
  if (role == 3) {
    float rv = (lane < 32) ? cAcc : (lane == 32 ? dAcc : 0.f);
    rv += __shfl_down(rv, 32);
    rv += __shfl_down(rv, 16);
    rv += __shfl_down(rv, 8);
    rv += __shfl_down(rv, 4);
    rv += __shfl_down(rv, 2);
    rv += __shfl_down(rv, 1);
    if (lane == 0) scostp[p] = rv;
  }
  // Full __syncthreads: drains wsK/wskv global stores (forward reads them via
  // global) and fences union re-use.
  __syncthreads();

  // ---------------- forward: role-0 wave per problem, barrier-free ----------------
  if (role == 0) {
    {  // preload K_0, k_0 into buf 0 (transposed, stride 36)
      const float4* src = (const float4*)(wsK + ((size_t)b * Td) * 512);
      float4 ka = src[lane * 2], kb = src[lane * 2 + 1];
      int jj = lane >> 1, ib = (lane & 1) * 8;
      float* kt2 = U[p].fw.K2T[0];
      kt2[(ib + 0) * 36 + jj] = ka.x; kt2[(ib + 1) * 36 + jj] = ka.y;
      kt2[(ib + 2) * 36 + jj] = ka.z; kt2[(ib + 3) * 36 + jj] = ka.w;
      kt2[(ib + 4) * 36 + jj] = kb.x; kt2[(ib + 5) * 36 + jj] = kb.y;
      kt2[(ib + 6) * 36 + jj] = kb.z; kt2[(ib + 7) * 36 + jj] = kb.w;
      if (lane < 16) U[p].fw.kv2[0][lane] = wskv[(size_t)b * Td * 16 + lane];
    }
    float xr = (lane < 32) ? scx[p][0][lane] : 0.f;
    for (int t = 0; t < Td; ++t) {
      const int cur = t & 1, nxt = cur ^ 1;
      float4 pa, pb;
      float pk;
      if (t < Td - 1) {  // prefetch K_{t+1}
        const float4* src = (const float4*)(wsK + ((size_t)b * Td + t + 1) * 512);
        pa = src[lane * 2];
        pb = src[lane * 2 + 1];
        if (lane < 16) pk = wskv[((size_t)b * Td + t + 1) * 16 + lane];
      }
      if (lane < 32) {  // d = x - cx; stash x; emit x
        U[p].fw.d[lane] = xr - scx[p][t][lane];
        U[p].fw.xs[lane] = xr;
        out[XOFF + ((size_t)b * Td + t) * 32 + lane] = xr;
      }
      if (lane < 16) {  // u = k + K d; emit u
        float uv = U[p].fw.kv2[cur][lane];
        const float* kr = &U[p].fw.K2T[cur][lane * 36];
#pragma unroll
        for (int j4 = 0; j4 < 8; ++j4) {
          float4 kk = *(const float4*)&kr[j4 * 4];
          float4 dd = *(const float4*)&U[p].fw.d[j4 * 4];
          uv += kk.x * dd.x + kk.y * dd.y + kk.z * dd.z + kk.w * dd.w;
        }
        U[p].fw.uu[lane] = uv;
        out[UOFF + ((size_t)b * Td + t) * 16 + lane] = uv;
      }
      if (lane < 32) {  // x' = A x + B u
        float acc = 0.f;
#pragma unroll
        for (int j4 = 0; j4 < 8; ++j4) {
          float4 ff = *(const float4*)&sFf[lane][j4 * 4];
          float4 xv = *(const float4*)&U[p].fw.xs[j4 * 4];
          acc += ff.x * xv.x + ff.y * xv.y + ff.z * xv.z + ff.w * xv.w;
        }
#pragma unroll
        for (int j4 = 0; j4 < 4; ++j4) {
          float4 ff = *(const float4*)&sFf[lane][32 + j4 * 4];
          float4 uv = *(const float4*)&U[p].fw.uu[j4 * 4];
          acc += ff.x * uv.x + ff.y * uv.y + ff.z * uv.z + ff.w * uv.w;
        }
        xr = acc;
      }
      if (t < Td - 1) {  // commit K_{t+1}
        int jj = lane >> 1, ib = (lane & 1) * 8;
        float* kt2 = U[p].fw.K2T[nxt];
        kt2[(ib + 0) * 36 + jj] = pa.x; kt2[(ib + 1) * 36 + jj] = pa.y;
        kt2[(ib + 2) * 36 + jj] = pa.z; kt2[(ib + 3) * 36 + jj] = pa.w;
        kt2[(ib + 4) * 36 + jj] = pb.x; kt2[(ib + 5) * 36 + jj] = pb.y;
        kt2[(ib + 6) * 36 + jj] = pb.z; kt2[(ib + 7) * 36 + jj] = pb.w;
        if (lane < 16) U[p].fw.kv2[nxt][lane] = pk;
      }
    }
    if (lane == 0) out[COFF + b] = scostp[p];
  }
}

extern "C" void kernel_launch(void* const* d_in, const int* in_sizes, int n_in,
                              void* d_out, int out_size, void* d_ws, size_t ws_size,
                              hipStream_t stream) {
  const float* x_init = (const float*)d_in[0];
  const float* Qg = (const float*)d_in[1];
  const float* pg = (const float*)d_in[2];
  const float* Ag = (const float*)d_in[3];
  const float* Bg = (const float*)d_in[4];
  float* out = (float*)d_out;
  float* wsK = (float*)d_ws;
  float* wskv = wsK + (size_t)NBd * Td * NSd * NCd;
  lqr_kernel<<<NBd / 2, 512, 0, stream>>>(x_init, Qg, pg, Ag, Bg, out, wsK, wskv);
}

// Round 5
// 620.822 us; speedup vs baseline: 1.0507x; 1.0507x over previous
//
#include <hip/hip_runtime.h>

// LQR2: NS=32, NC=16, T=64, NB=512, NSC=48
// out: x[512][64][32] | u[512][64][16] | cost[512]
// ws:  K^T fp32 [512][64][32][16]  then k fp32 [512][64][16]
//
// R9 == R8 resubmitted (bench infra failed twice; no kernel verdict).
// R8: back to 256-thr/1-problem blocks (R7's 512-thr fusion regressed: shared
// barrier locked two problems into lockstep and killed inter-block slip).
//  - V eliminated: WT = F^T V = S1 + S2*K with S1=F^T*Qxx, S2=F^T*Qxu
//    computed by the (otherwise idle) tile waves DURING the solve (phase B).
//    Removes P4 + V cvt + mirror from the solver critical path.
//  - f32 handoff tiles (QuuT/QdT/S1T) stored column-major: acc->float4 store,
//    float4 reads. Identical values, 4x fewer LDS ops.
//  - Solve: backsolve reuses elimination's inv[r] (same pivot value -> same
//    rcp -> bit-identical), removing 15 serial rcps.
// R6: 2 lgkm-only barriers/step; P0+P1 fused wave-local; solver w3.
// R5: LDS padding TP=40 bf16 / SQS=52 f32.
// R4: analytic cost during backward; wave-synchronous forward.

#define NSd 32
#define NCd 16
#define Td 64
#define NBd 512
#define SQS 52  // padded row stride (floats) for sQ / sFf
#define TP 40   // padded row stride (bf16) for MFMA tiles
#define FP 20   // padded row stride (floats) for f32 handoff tiles

typedef __bf16 bf16x8 __attribute__((ext_vector_type(8)));
typedef __bf16 bf16x4 __attribute__((ext_vector_type(4)));
typedef float f32x4 __attribute__((ext_vector_type(4)));

#define MFMA16(a, b, c) __builtin_amdgcn_mfma_f32_16x16x32_bf16(a, b, c, 0, 0, 0)

#define XOFF ((size_t)0)
#define UOFF ((size_t)NBd * Td * NSd)
#define COFF (UOFF + (size_t)NBd * Td * NCd)

__device__ __forceinline__ float rdl(float v, int l) {
  return __uint_as_float(__builtin_amdgcn_readlane(__float_as_uint(v), l));
}

// LDS-only barrier: does NOT drain vmcnt; all in-loop cross-wave deps are LDS.
__device__ __forceinline__ void bar_lgkm() {
  asm volatile("s_waitcnt lgkmcnt(0)\n\ts_barrier" ::: "memory");
}

struct BW {
  __bf16 FTh[48][TP], FTl[48][TP];
  __bf16 WTh[48][TP], WTl[48][TP];
  __bf16 Xh[32][TP], Xl[32][TP];    // Qxu rows (solver rhs / vn)
  __bf16 KTh[32][TP], KTl[32][TP];  // K^T rows (x-major); cols 16..31 zero
  __bf16 XTh[16][TP], XTl[16][TP];  // Qxu^T rows (u-major) for S2 B-operand
  __bf16 S2h[48][TP], S2l[48][TP];  // F^T*Qxu; cols 16..31 zero
  float S1T[6][16][FP];             // F^T*Qxx tiles (I,J), col-major
  float QdT[3][16][FP];             // Qxx blocks (0,0),(0,1),(1,1), col-major
  float Qd1R[16][FP];               // Qxx block (0,1), row-major
  float QuuT[16][FP];               // Quu, col-major
  float qt[48];
  float vv[32];
};
struct FW {  // overlays dead backward fragments
  float K2T[2][16 * 36];  // row stride 36 (bank-conflict pad, 16B aligned)
  float kv2[2][16];
  float d[32];
  float xs[32];
  float uu[16];
};
union LdsU {
  BW bw;
  FW fw;
};

// padded sQ store: linear float4 index i (of 576) -> row i/12, col (i%12)*4
#define SQSTORE(i, v)                            \
  do {                                           \
    int _r = (i) / 12, _c = (i) - _r * 12;       \
    *(float4*)&sQ[_r * SQS + _c * 4] = (v);      \
  } while (0)

__global__ __launch_bounds__(256, 2) void lqr_kernel(
    const float* __restrict__ x_init, const float* __restrict__ Qg,
    const float* __restrict__ pg, const float* __restrict__ Ag,
    const float* __restrict__ Bg, float* __restrict__ out,
    float* __restrict__ wsK, float* __restrict__ wskv) {
  const int b = blockIdx.x;
  const int tid = threadIdx.x;
  const int w = tid >> 6;
  const int lane = tid & 63;
  const int fn = lane & 15;
  const int quad = lane >> 4;
  const int k0 = quad * 8;

  __shared__ __attribute__((aligned(16))) float sQ[48 * SQS];
  __shared__ __attribute__((aligned(16))) float scx[Td][NSd];
  __shared__ __attribute__((aligned(16))) float sFf[NSd][SQS];
  __shared__ __attribute__((aligned(16))) LdsU U;
  __shared__ float scostp[1];

  // ---------------- setup ----------------
  for (int idx = tid; idx < 1536; idx += 256) {
    int i = idx / 48, j = idx - i * 48;
    sFf[i][j] = (j < 32) ? Ag[i * 32 + j] : Bg[i * 16 + (j - 32)];
  }
  for (int idx = tid; idx < 1536; idx += 256) {
    int a = idx >> 5, k = idx & 31;
    float f = (a < 32) ? Ag[k * 32 + a] : Bg[k * 16 + (a - 32)];
    __bf16 h = (__bf16)f;
    U.bw.FTh[a][k] = h;
    U.bw.FTl[a][k] = (__bf16)(f - (float)h);
  }
  // zero: KT (read k0..31 in WT-stage), S2 (read before first write, cols
  // 16..31 must stay zero), S1T (read before first write)
  for (int idx = tid; idx < 1536; idx += 256) {
    int r = idx >> 5, c = idx & 31;
    __bf16 z = (__bf16)0.f;
    U.bw.S2h[r][c] = z;
    U.bw.S2l[r][c] = z;
    if (r < 32) {
      U.bw.KTh[r][c] = z;
      U.bw.KTl[r][c] = z;
    }
  }
  for (int idx = tid; idx < 6 * 16 * FP; idx += 256) ((float*)U.bw.S1T)[idx] = 0.f;
  if (tid < 32) {
    scx[0][tid] = x_init[b * 32 + tid];
    U.bw.vv[tid] = 0.f;
  }
  {  // stage Q[b,63]
    const float4* src = (const float4*)(Qg + ((size_t)b * Td + 63) * 2304);
    float4 v0 = src[tid];
    float4 v1 = src[tid + 256];
    SQSTORE(tid, v0);
    SQSTORE(tid + 256, v1);
    if (tid < 64) {
      float4 v2 = src[tid + 512];
      SQSTORE(tid + 512, v2);
    }
  }
  float ppf = 0.f;
  if (w == 3 && lane < 48) ppf = pg[((size_t)b * Td + 63) * 48 + lane];
  __syncthreads();

  // cx rollout, wave-0 synchronous
  if (w == 0) {
    for (int t2 = 0; t2 < Td - 1; ++t2) {
      if (lane < 32) {
        float acc = 0.f;
#pragma unroll
        for (int j = 0; j < 32; j += 4) {
          float4 a4 = *(const float4*)&sFf[lane][j];
          acc += a4.x * scx[t2][j] + a4.y * scx[t2][j + 1] +
                 a4.z * scx[t2][j + 2] + a4.w * scx[t2][j + 3];
        }
        scx[t2 + 1][lane] = acc;
      }
    }
  }
  __syncthreads();

  float cAcc = 0.f;  // w3 lanes<32: sum_t 0.5*cx'(p + 0.5*Q*cx) terms
  float dAcc = 0.f;  // w3 lane32: sum_t 0.5*qu.kt

  // ---------------- backward Riccati: 2 barriers/step ----------------
  for (int t = Td - 1; t >= 0; --t) {
    float4 pf0, pf1, pf2;
    float ppfn;
    if (t > 0) {
      if (w < 3) {  // 192 threads x 3 float4 = 576 = full Q tile
        const float4* src = (const float4*)(Qg + ((size_t)b * Td + (t - 1)) * 2304);
        pf0 = src[tid];
        pf1 = src[tid + 192];
        pf2 = src[tid + 384];
      } else if (lane < 48) {
        ppfn = pg[((size_t)b * Td + t - 1) * 48 + lane];
      }
    }

    // ---- Phase A: WT = S1 + S2*K, then Qt = sQ + WT*F; qt on w3 ----
    if (w < 3) {
      const int I = w;
      {  // WT-stage: row-block I, both col halves J
        bf16x8 aH = *(const bf16x8*)&U.bw.S2h[16 * I + fn][k0];
        bf16x8 aL = *(const bf16x8*)&U.bw.S2l[16 * I + fn][k0];
#pragma unroll
        for (int J = 0; J < 2; ++J) {
          bf16x8 bH = *(const bf16x8*)&U.bw.KTh[16 * J + fn][k0];
          bf16x8 bL = *(const bf16x8*)&U.bw.KTl[16 * J + fn][k0];
          float4 s1 = *(const float4*)&U.bw.S1T[I * 2 + J][fn][4 * quad];
          f32x4 acc = {s1.x, s1.y, s1.z, s1.w};
          acc = MFMA16(aL, bH, acc);
          acc = MFMA16(aH, bL, acc);
          acc = MFMA16(aH, bH, acc);
#pragma unroll
          for (int r = 0; r < 4; ++r) {
            float v = acc[r];
            __bf16 h = (__bf16)v;
            U.bw.WTh[16 * I + 4 * quad + r][16 * J + fn] = h;
            U.bw.WTl[16 * I + 4 * quad + r][16 * J + fn] = (__bf16)(v - (float)h);
          }
        }
      }
      // Qt-stage (same wave reads only its own WT rows; lgkm dep, no barrier)
      bf16x8 wH = *(const bf16x8*)&U.bw.WTh[16 * I + fn][k0];
      bf16x8 wL = *(const bf16x8*)&U.bw.WTl[16 * I + fn][k0];
      if (I == 2) {  // (2,2) -> QuuT col-major f32
        bf16x8 bH = *(const bf16x8*)&U.bw.FTh[32 + fn][k0];
        bf16x8 bL = *(const bf16x8*)&U.bw.FTl[32 + fn][k0];
        f32x4 acc;
#pragma unroll
        for (int r = 0; r < 4; ++r)
          acc[r] = sQ[(32 + 4 * quad + r) * SQS + 32 + fn];
        acc = MFMA16(wL, bH, acc);
        acc = MFMA16(wH, bL, acc);
        acc = MFMA16(wH, bH, acc);
        float4 st = {acc[0], acc[1], acc[2], acc[3]};
        *(float4*)&U.bw.QuuT[fn][4 * quad] = st;
      } else {
        {  // diag tile (I,I) -> QdT[0] (I=0) / QdT[2] (I=1), col-major
          bf16x8 bH = *(const bf16x8*)&U.bw.FTh[16 * I + fn][k0];
          bf16x8 bL = *(const bf16x8*)&U.bw.FTl[16 * I + fn][k0];
          f32x4 acc;
#pragma unroll
          for (int r = 0; r < 4; ++r)
            acc[r] = sQ[(16 * I + 4 * quad + r) * SQS + 16 * I + fn];
          acc = MFMA16(wL, bH, acc);
          acc = MFMA16(wH, bL, acc);
          acc = MFMA16(wH, bH, acc);
          float4 st = {acc[0], acc[1], acc[2], acc[3]};
          *(float4*)&U.bw.QdT[I * 2][fn][4 * quad] = st;
        }
        if (I == 0) {  // (0,1) -> QdT[1] col-major + Qd1R row-major
          bf16x8 bH = *(const bf16x8*)&U.bw.FTh[16 + fn][k0];
          bf16x8 bL = *(const bf16x8*)&U.bw.FTl[16 + fn][k0];
          f32x4 acc;
#pragma unroll
          for (int r = 0; r < 4; ++r)
            acc[r] = sQ[(4 * quad + r) * SQS + 16 + fn];
          acc = MFMA16(wL, bH, acc);
          acc = MFMA16(wH, bL, acc);
          acc = MFMA16(wH, bH, acc);
          float4 st = {acc[0], acc[1], acc[2], acc[3]};
          *(float4*)&U.bw.QdT[1][fn][4 * quad] = st;
#pragma unroll
          for (int r = 0; r < 4; ++r) U.bw.Qd1R[4 * quad + r][fn] = acc[r];
        }
        {  // (I,2) -> X rows (row-major hi/lo) + XT (u-major, b64 stores)
          bf16x8 bH = *(const bf16x8*)&U.bw.FTh[32 + fn][k0];
          bf16x8 bL = *(const bf16x8*)&U.bw.FTl[32 + fn][k0];
          f32x4 acc;
#pragma unroll
          for (int r = 0; r < 4; ++r)
            acc[r] = sQ[(16 * I + 4 * quad + r) * SQS + 32 + fn];
          acc = MFMA16(wL, bH, acc);
          acc = MFMA16(wH, bL, acc);
          acc = MFMA16(wH, bH, acc);
          bf16x4 th, tl;
#pragma unroll
          for (int r = 0; r < 4; ++r) {
            float v = acc[r];
            __bf16 h = (__bf16)v;
            __bf16 l = (__bf16)(v - (float)h);
            U.bw.Xh[16 * I + 4 * quad + r][fn] = h;
            U.bw.Xl[16 * I + 4 * quad + r][fn] = l;
            th[r] = h;
            tl[r] = l;
          }
          *(bf16x4*)&U.bw.XTh[fn][16 * I + 4 * quad] = th;
          *(bf16x4*)&U.bw.XTl[fn][16 * I + 4 * quad] = tl;
        }
      }
    } else if (lane < 48) {  // w3: qt vector + cost const term
      float acc1 = ppf;  // p + Q*cxu
#pragma unroll
      for (int k = 0; k < 32; ++k) acc1 += sQ[k * SQS + lane] * scx[t][k];
      if (lane < 32) cAcc += 0.5f * scx[t][lane] * (acc1 + ppf);
      float acc = acc1;
#pragma unroll
      for (int k = 0; k < 32; ++k) acc += U.bw.vv[k] * sFf[k][lane];
      U.bw.qt[lane] = acc;
    }
    bar_lgkm();  // B2

    // ---- Phase B: tile waves commit sQ + S1/S2 precompute; w3 solves ----
    if (t > 0) {
      if (w < 3) {
        SQSTORE(tid, pf0);
        SQSTORE(tid + 192, pf1);
        SQSTORE(tid + 384, pf2);
      } else if (lane < 48) {
        ppf = ppfn;
      }
    }
    if (w < 3 && t > 0) {
      // S1 = F^T * Qxx (6 tiles), S2 = F^T * Qxu (3 tiles) for next step,
      // computed in the solve's shadow.
      const int I = w;
      bf16x8 aH = *(const bf16x8*)&U.bw.FTh[16 * I + fn][k0];
      bf16x8 aL = *(const bf16x8*)&U.bw.FTl[16 * I + fn][k0];
#pragma unroll
      for (int J = 0; J < 2; ++J) {
        // B[k][fn] = Qxx[k][16J+fn]; k-slice k0..k0+7 from col-major/row-major
        // f32 images ((1,0) block via symmetry, as the old V-mirror did).
        const float* bsrc;
        if (J == 0)
          bsrc = (quad < 2) ? &U.bw.QdT[0][fn][0] : &U.bw.Qd1R[fn][0];
        else
          bsrc = (quad < 2) ? &U.bw.QdT[1][fn][0] : &U.bw.QdT[2][fn][0];
        const int off = (quad & 1) * 8;
        float4 c0 = *(const float4*)&bsrc[off];
        float4 c1 = *(const float4*)&bsrc[off + 4];
        float bf[8] = {c0.x, c0.y, c0.z, c0.w, c1.x, c1.y, c1.z, c1.w};
        bf16x8 bH, bL;
#pragma unroll
        for (int j = 0; j < 8; ++j) {
          __bf16 h = (__bf16)bf[j];
          bH[j] = h;
          bL[j] = (__bf16)(bf[j] - (float)h);
        }
        f32x4 acc = {0.f, 0.f, 0.f, 0.f};
        acc = MFMA16(aL, bH, acc);
        acc = MFMA16(aH, bL, acc);
        acc = MFMA16(aH, bH, acc);
        float4 st = {acc[0], acc[1], acc[2], acc[3]};
        *(float4*)&U.bw.S1T[I * 2 + J][fn][4 * quad] = st;
      }
      {  // S2 tile I
        bf16x8 bH = *(const bf16x8*)&U.bw.XTh[fn][k0];
        bf16x8 bL = *(const bf16x8*)&U.bw.XTl[fn][k0];
        f32x4 acc = {0.f, 0.f, 0.f, 0.f};
        acc = MFMA16(aL, bH, acc);
        acc = MFMA16(aH, bL, acc);
        acc = MFMA16(aH, bH, acc);
#pragma unroll
        for (int r = 0; r < 4; ++r) {
          float v = acc[r];
          __bf16 h = (__bf16)v;
          U.bw.S2h[16 * I + 4 * quad + r][fn] = h;
          U.bw.S2l[16 * I + 4 * quad + r][fn] = (__bf16)(v - (float)h);
        }
      }
    }
    if (w == 3) {
      // solve Quu * X = [Qux | qu] via readlane-broadcast elimination
      float rhs[16];
      if (lane < 32) {
        bf16x8 xh0 = *(const bf16x8*)&U.bw.Xh[lane][0];
        bf16x8 xh1 = *(const bf16x8*)&U.bw.Xh[lane][8];
        bf16x8 xl0 = *(const bf16x8*)&U.bw.Xl[lane][0];
        bf16x8 xl1 = *(const bf16x8*)&U.bw.Xl[lane][8];
#pragma unroll
        for (int i = 0; i < 8; ++i) {
          rhs[i] = (float)xh0[i] + (float)xl0[i];
          rhs[8 + i] = (float)xh1[i] + (float)xl1[i];
        }
      } else {
#pragma unroll
        for (int i = 0; i < 16; ++i) rhs[i] = U.bw.qt[32 + i];
      }
      float quu[16];
      *(float4*)&quu[0] = *(const float4*)&U.bw.QuuT[fn][0];
      *(float4*)&quu[4] = *(const float4*)&U.bw.QuuT[fn][4];
      *(float4*)&quu[8] = *(const float4*)&U.bw.QuuT[fn][8];
      *(float4*)&quu[12] = *(const float4*)&U.bw.QuuT[fn][12];
      float inv[16];
#pragma unroll
      for (int r = 0; r < 15; ++r) {
        inv[r] = __builtin_amdgcn_rcpf(rdl(quu[r], r));
#pragma unroll
        for (int i = r + 1; i < 16; ++i) {
          float m = rdl(quu[i], r) * inv[r];
          rhs[i] -= m * rhs[r];
          quu[i] -= m * quu[r];
        }
      }
      inv[15] = __builtin_amdgcn_rcpf(rdl(quu[15], 15));
      float xx[16];
#pragma unroll
      for (int r = 15; r >= 0; --r) {
        float s = rhs[r];
#pragma unroll
        for (int c = r + 1; c < 16; ++c) s -= rdl(quu[r], c) * xx[c];
        xx[r] = s * inv[r];
      }
      if (lane < 32) {  // Kt^T bf16 to LDS + fp32 K to ws
        bf16x8 h0, l0, h1, l1;
#pragma unroll
        for (int u = 0; u < 8; ++u) {
          float kv = -xx[u];
          __bf16 hh = (__bf16)kv;
          h0[u] = hh;
          l0[u] = (__bf16)(kv - (float)hh);
          float kv2 = -xx[8 + u];
          __bf16 hh2 = (__bf16)kv2;
          h1[u] = hh2;
          l1[u] = (__bf16)(kv2 - (float)hh2);
        }
        *(bf16x8*)&U.bw.KTh[lane][0] = h0;
        *(bf16x8*)&U.bw.KTh[lane][8] = h1;
        *(bf16x8*)&U.bw.KTl[lane][0] = l0;
        *(bf16x8*)&U.bw.KTl[lane][8] = l1;
        float4* dst = (float4*)(wsK + (((size_t)b * Td + t) * 32 + lane) * 16);
        float4 v0 = {-xx[0], -xx[1], -xx[2], -xx[3]};
        float4 v1 = {-xx[4], -xx[5], -xx[6], -xx[7]};
        float4 v2 = {-xx[8], -xx[9], -xx[10], -xx[11]};
        float4 v3 = {-xx[12], -xx[13], -xx[14], -xx[15]};
        dst[0] = v0; dst[1] = v1; dst[2] = v2; dst[3] = v3;
      } else if (lane == 32) {  // kt to ws; cost delta term
        float4* dst = (float4*)(wskv + ((size_t)b * Td + t) * 16);
        float4 v0 = {-xx[0], -xx[1], -xx[2], -xx[3]};
        float4 v1 = {-xx[4], -xx[5], -xx[6], -xx[7]};
        float4 v2 = {-xx[8], -xx[9], -xx[10], -xx[11]};
        float4 v3 = {-xx[12], -xx[13], -xx[14], -xx[15]};
        dst[0] = v0; dst[1] = v1; dst[2] = v2; dst[3] = v3;
        float s = 0.f;
#pragma unroll
        for (int i = 0; i < 16; ++i) s += U.bw.qt[32 + i] * xx[i];
        dAcc -= 0.5f * s;
      }
      {  // vn = qx + Qxu*kt using local xx (kt lives in lane 32's xx)
        float acc = 0.f;
        bf16x8 xh0, xh1, xl0, xl1;
        if (lane < 32) {
          xh0 = *(const bf16x8*)&U.bw.Xh[lane][0];
          xh1 = *(const bf16x8*)&U.bw.Xh[lane][8];
          xl0 = *(const bf16x8*)&U.bw.Xl[lane][0];
          xl1 = *(const bf16x8*)&U.bw.Xl[lane][8];
          acc = U.bw.qt[lane];
        }
#pragma unroll
        for (int u = 0; u < 8; ++u) {
          float kt0 = -rdl(xx[u], 32);
          float kt1 = -rdl(xx[8 + u], 32);
          if (lane < 32) {
            acc += ((float)xh0[u] + (float)xl0[u]) * kt0;
            acc += ((float)xh1[u] + (float)xl1[u]) * kt1;
          }
        }
        if (lane < 32) U.bw.vv[lane] = acc;
      }
    }
    bar_lgkm();  // B3 (end of step)
  }

  // ---------------- cost partial, then union flips to forward ----------------
  if (w == 3) {
    float rv = (lane < 32) ? cAcc : (lane == 32 ? dAcc : 0.f);
    rv += __shfl_down(rv, 32);
    rv += __shfl_down(rv, 16);
    rv += __shfl_down(rv, 8);
    rv += __shfl_down(rv, 4);
    rv += __shfl_down(rv, 2);
    rv += __shfl_down(rv, 1);
    if (lane == 0) scostp[0] = rv;
  }
  // Full __syncthreads: drains wsK/wskv global stores (forward reads them via
  // global) and fences union re-use.
  __syncthreads();

  // ---------------- forward: wave-0 synchronous, barrier-free ----------------
  if (w == 0) {
    {  // preload K_0, k_0 into buf 0 (transposed, stride 36)
      const float4* src = (const float4*)(wsK + ((size_t)b * Td) * 512);
      float4 ka = src[lane * 2], kb = src[lane * 2 + 1];
      int jj = lane >> 1, ib = (lane & 1) * 8;
      float* kt2 = U.fw.K2T[0];
      kt2[(ib + 0) * 36 + jj] = ka.x; kt2[(ib + 1) * 36 + jj] = ka.y;
      kt2[(ib + 2) * 36 + jj] = ka.z; kt2[(ib + 3) * 36 + jj] = ka.w;
      kt2[(ib + 4) * 36 + jj] = kb.x; kt2[(ib + 5) * 36 + jj] = kb.y;
      kt2[(ib + 6) * 36 + jj] = kb.z; kt2[(ib + 7) * 36 + jj] = kb.w;
      if (lane < 16) U.fw.kv2[0][lane] = wskv[(size_t)b * Td * 16 + lane];
    }
    float xr = (lane < 32) ? scx[0][lane] : 0.f;
    for (int t = 0; t < Td; ++t) {
      const int cur = t & 1, nxt = cur ^ 1;
      float4 pa, pb;
      float pk;
      if (t < Td - 1) {  // prefetch K_{t+1}
        const float4* src = (const float4*)(wsK + ((size_t)b * Td + t + 1) * 512);
        pa = src[lane * 2];
        pb = src[lane * 2 + 1];
        if (lane < 16) pk = wskv[((size_t)b * Td + t + 1) * 16 + lane];
      }
      if (lane < 32) {  // d = x - cx; stash x; emit x
        U.fw.d[lane] = xr - scx[t][lane];
        U.fw.xs[lane] = xr;
        out[XOFF + ((size_t)b * Td + t) * 32 + lane] = xr;
      }
      if (lane < 16) {  // u = k + K d; emit u
        float uv = U.fw.kv2[cur][lane];
        const float* kr = &U.fw.K2T[cur][lane * 36];
#pragma unroll
        for (int j4 = 0; j4 < 8; ++j4) {
          float4 kk = *(const float4*)&kr[j4 * 4];
          float4 dd = *(const float4*)&U.fw.d[j4 * 4];
          uv += kk.x * dd.x + kk.y * dd.y + kk.z * dd.z + kk.w * dd.w;
        }
        U.fw.uu[lane] = uv;
        out[UOFF + ((size_t)b * Td + t) * 16 + lane] = uv;
      }
      if (lane < 32) {  // x' = A x + B u
        float acc = 0.f;
#pragma unroll
        for (int j4 = 0; j4 < 8; ++j4) {
          float4 ff = *(const float4*)&sFf[lane][j4 * 4];
          float4 xv = *(const float4*)&U.fw.xs[j4 * 4];
          acc += ff.x * xv.x + ff.y * xv.y + ff.z * xv.z + ff.w * xv.w;
        }
#pragma unroll
        for (int j4 = 0; j4 < 4; ++j4) {
          float4 ff = *(const float4*)&sFf[lane][32 + j4 * 4];
          float4 uv = *(const float4*)&U.fw.uu[j4 * 4];
          acc += ff.x * uv.x + ff.y * uv.y + ff.z * uv.z + ff.w * uv.w;
        }
        xr = acc;
      }
      if (t < Td - 1) {  // commit K_{t+1}
        int jj = lane >> 1, ib = (lane & 1) * 8;
        float* kt2 = U.fw.K2T[nxt];
        kt2[(ib + 0) * 36 + jj] = pa.x; kt2[(ib + 1) * 36 + jj] = pa.y;
        kt2[(ib + 2) * 36 + jj] = pa.z; kt2[(ib + 3) * 36 + jj] = pa.w;
        kt2[(ib + 4) * 36 + jj] = pb.x; kt2[(ib + 5) * 36 + jj] = pb.y;
        kt2[(ib + 6) * 36 + jj] = pb.z; kt2[(ib + 7) * 36 + jj] = pb.w;
        if (lane < 16) U.fw.kv2[nxt][lane] = pk;
      }
    }
    if (lane == 0) out[COFF + b] = scostp[0];
  }
}

extern "C" void kernel_launch(void* const* d_in, const int* in_sizes, int n_in,
                              void* d_out, int out_size, void* d_ws, size_t ws_size,
                              hipStream_t stream) {
  const float* x_init = (const float*)d_in[0];
  const float* Qg = (const float*)d_in[1];
  const float* pg = (const float*)d_in[2];
  const float* Ag = (const float*)d_in[3];
  const float* Bg = (const float*)d_in[4];
  float* out = (float*)d_out;
  float* wsK = (float*)d_ws;
  float* wskv = wsK + (size_t)NBd * Td * NSd * NCd;
  lqr_kernel<<<NBd, 256, 0, stream>>>(x_init, Qg, pg, Ag, Bg, out, wsK, wskv);
}